// Round 1
// baseline (1039.027 us; speedup 1.0000x reference)
//
#include <hip/hip_runtime.h>
#include <math.h>

// Problem constants
#define DIMC   768
#define NHEAD  12
#define HDIM   64
#define NBATCH 8
#define SEQ    1024
#define SCALE  0.125f
#define QKV_ELEMS (NBATCH * NHEAD * SEQ * HDIM)   // 6291456 floats per tensor

// ---------------------------------------------------------------------------
// Kernel 1: QKV projection.  C[m, c] = sum_k x[m,k] * w_qkv[c,k]
//   m in [0, 8192) = (b, n); c in [0, 2304) = (which, h, d)
//   Scatters into q/k/v buffers laid out (B, H, N, HD).
// Tile 128x128, K-chunk 16, 256 threads (16x16), 8x8 micro-tile.
// ---------------------------------------------------------------------------
__global__ __launch_bounds__(256) void qkv_gemm_kernel(
    const float* __restrict__ x, const float* __restrict__ wqkv,
    float* __restrict__ qb, float* __restrict__ kb, float* __restrict__ vb)
{
    __shared__ float As[16][132];
    __shared__ float Bs[16][132];
    const int t  = threadIdx.x;
    const int tx = t & 15;
    const int ty = t >> 4;
    const int c0 = blockIdx.x * 128;
    const int m0 = blockIdx.y * 128;

    float acc[8][8];
    #pragma unroll
    for (int i = 0; i < 8; ++i)
        #pragma unroll
        for (int j = 0; j < 8; ++j) acc[i][j] = 0.f;

    for (int k0 = 0; k0 < DIMC; k0 += 16) {
        #pragma unroll
        for (int s = 0; s < 2; ++s) {
            const int f   = t + s * 256;          // 0..511 float4 slots
            const int row = f >> 2;               // 0..127
            const int col = (f & 3) << 2;         // 0,4,8,12
            float4 av = *(const float4*)(x    + (size_t)(m0 + row) * DIMC + k0 + col);
            float4 bv = *(const float4*)(wqkv + (size_t)(c0 + row) * DIMC + k0 + col);
            As[col + 0][row] = av.x; As[col + 1][row] = av.y;
            As[col + 2][row] = av.z; As[col + 3][row] = av.w;
            Bs[col + 0][row] = bv.x; Bs[col + 1][row] = bv.y;
            Bs[col + 2][row] = bv.z; Bs[col + 3][row] = bv.w;
        }
        __syncthreads();
        #pragma unroll
        for (int kk = 0; kk < 16; ++kk) {
            float4 a0 = *(const float4*)&As[kk][8 * ty];
            float4 a1 = *(const float4*)&As[kk][8 * ty + 4];
            float4 b0 = *(const float4*)&Bs[kk][8 * tx];
            float4 b1 = *(const float4*)&Bs[kk][8 * tx + 4];
            const float a[8]  = {a0.x, a0.y, a0.z, a0.w, a1.x, a1.y, a1.z, a1.w};
            const float bb[8] = {b0.x, b0.y, b0.z, b0.w, b1.x, b1.y, b1.z, b1.w};
            #pragma unroll
            for (int i = 0; i < 8; ++i)
                #pragma unroll
                for (int j = 0; j < 8; ++j)
                    acc[i][j] = fmaf(a[i], bb[j], acc[i][j]);
        }
        __syncthreads();
    }

    // Epilogue: scatter into q/k/v (B,H,N,HD)
    const int b  = m0 >> 10;          // m0 / 1024
    const int n0 = m0 & 1023;
    #pragma unroll
    for (int jj = 0; jj < 2; ++jj) {
        const int cg    = c0 + 8 * tx + 4 * jj;   // global out column (4-aligned)
        const int which = cg / DIMC;
        const int rem   = cg - which * DIMC;
        const int h     = rem >> 6;
        const int d     = rem & 63;
        float* dst  = (which == 0) ? qb : (which == 1) ? kb : vb;
        float* base = dst + (((size_t)b * NHEAD + h) * SEQ) * HDIM + d;
        #pragma unroll
        for (int i = 0; i < 8; ++i) {
            const int n = n0 + 8 * ty + i;
            float4 v4 = make_float4(acc[i][4 * jj + 0], acc[i][4 * jj + 1],
                                    acc[i][4 * jj + 2], acc[i][4 * jj + 3]);
            *(float4*)(base + (size_t)n * HDIM) = v4;
        }
    }
}

// ---------------------------------------------------------------------------
// Kernel 2: flash-style attention with sigmoid mask gating.
// One block = (b, h, 64-row Q tile). 256 threads (16x16), 4x4 micro-tiles.
// Online softmax over 16 chunks of 64 keys. Ps aliases Ks (52 KB LDS total,
// stays under the 64 KB static-LDS-per-block limit).
// Writes ao laid out (B, N, DIMC) for the final projection.
// ---------------------------------------------------------------------------
__global__ __launch_bounds__(256) void flash_attn_kernel(
    const float* __restrict__ qb, const float* __restrict__ kb,
    const float* __restrict__ vb, const float* __restrict__ mask,
    float* __restrict__ ao)
{
    __shared__ float Qs[64][68];
    __shared__ float KPs[64][68];   // K chunk, later reused for P
    __shared__ float Vs[64][68];

    const int t  = threadIdx.x;
    const int tx = t & 15;
    const int ty = t >> 4;
    const int bid = blockIdx.x;               // b*H*16 + h*16 + qt
    const int qt = bid & 15;
    const int h  = (bid >> 4) % NHEAD;
    const int b  = bid / (16 * NHEAD);
    const int q0 = qt * 64;

    const size_t head_off = (((size_t)b * NHEAD + h) * SEQ) * HDIM;
    const float* qbase = qb + head_off;

    // Load Q tile, pre-scaled by SCALE
    #pragma unroll
    for (int s = 0; s < 4; ++s) {
        const int f   = t + s * 256;          // 0..1023 float4 slots
        const int row = f >> 4;               // 0..63
        const int col = (f & 15) << 2;        // 0..60
        float4 v4 = *(const float4*)(qbase + (size_t)(q0 + row) * HDIM + col);
        *(float4*)&Qs[row][col] =
            make_float4(v4.x * SCALE, v4.y * SCALE, v4.z * SCALE, v4.w * SCALE);
    }

    float m_i[4], l_i[4], o[4][4];
    #pragma unroll
    for (int i = 0; i < 4; ++i) {
        m_i[i] = -1e30f;
        l_i[i] = 0.f;
        #pragma unroll
        for (int j = 0; j < 4; ++j) o[i][j] = 0.f;
    }

    for (int kt = 0; kt < 16; ++kt) {
        __syncthreads();   // protect Vs / KPs(P) from previous iteration readers
        const float* kbase = kb + head_off + (size_t)(kt * 64) * HDIM;
        const float* vbase = vb + head_off + (size_t)(kt * 64) * HDIM;
        #pragma unroll
        for (int s = 0; s < 4; ++s) {
            const int f   = t + s * 256;
            const int row = f >> 4;
            const int col = (f & 15) << 2;
            *(float4*)&KPs[row][col] = *(const float4*)(kbase + (size_t)row * HDIM + col);
            *(float4*)&Vs[row][col]  = *(const float4*)(vbase + (size_t)row * HDIM + col);
        }
        __syncthreads();

        // S = (Q*SCALE) . K^T  for rows 4ty+i, chunk cols 4tx+j
        float sc[4][4];
        #pragma unroll
        for (int i = 0; i < 4; ++i)
            #pragma unroll
            for (int j = 0; j < 4; ++j) sc[i][j] = 0.f;
        #pragma unroll
        for (int kk = 0; kk < 64; kk += 4) {
            float4 a[4], bv[4];
            #pragma unroll
            for (int i = 0; i < 4; ++i) a[i]  = *(const float4*)&Qs[4 * ty + i][kk];
            #pragma unroll
            for (int j = 0; j < 4; ++j) bv[j] = *(const float4*)&KPs[4 * tx + j][kk];
            #pragma unroll
            for (int i = 0; i < 4; ++i)
                #pragma unroll
                for (int j = 0; j < 4; ++j) {
                    sc[i][j] = fmaf(a[i].x, bv[j].x, sc[i][j]);
                    sc[i][j] = fmaf(a[i].y, bv[j].y, sc[i][j]);
                    sc[i][j] = fmaf(a[i].z, bv[j].z, sc[i][j]);
                    sc[i][j] = fmaf(a[i].w, bv[j].w, sc[i][j]);
                }
        }

        // sigmoid mask gating + online softmax update
        #pragma unroll
        for (int i = 0; i < 4; ++i) {
            const float* mrow = mask + ((size_t)h * SEQ + (q0 + 4 * ty + i)) * SEQ
                                     + kt * 64 + 4 * tx;
            float4 mv = *(const float4*)mrow;
            sc[i][0] *= 1.f / (1.f + __expf(-mv.x));
            sc[i][1] *= 1.f / (1.f + __expf(-mv.y));
            sc[i][2] *= 1.f / (1.f + __expf(-mv.z));
            sc[i][3] *= 1.f / (1.f + __expf(-mv.w));

            float mx = fmaxf(fmaxf(sc[i][0], sc[i][1]), fmaxf(sc[i][2], sc[i][3]));
            #pragma unroll
            for (int off = 1; off < 16; off <<= 1)
                mx = fmaxf(mx, __shfl_xor(mx, off, 64));
            const float mnew  = fmaxf(m_i[i], mx);
            const float alpha = __expf(m_i[i] - mnew);
            float rs = 0.f;
            #pragma unroll
            for (int j = 0; j < 4; ++j) {
                const float p = __expf(sc[i][j] - mnew);
                sc[i][j] = p;
                rs += p;
            }
            #pragma unroll
            for (int off = 1; off < 16; off <<= 1)
                rs += __shfl_xor(rs, off, 64);
            l_i[i] = l_i[i] * alpha + rs;
            m_i[i] = mnew;
            #pragma unroll
            for (int j = 0; j < 4; ++j) o[i][j] *= alpha;
        }

        __syncthreads();   // everyone done reading K from KPs
        #pragma unroll
        for (int i = 0; i < 4; ++i)
            *(float4*)&KPs[4 * ty + i][4 * tx] =
                make_float4(sc[i][0], sc[i][1], sc[i][2], sc[i][3]);
        __syncthreads();

        // O += P . V   (o cols = head dims 4tx+j)
        #pragma unroll
        for (int kk = 0; kk < 64; kk += 4) {
            float4 a[4], bv[4];
            #pragma unroll
            for (int i = 0; i < 4; ++i) a[i]  = *(const float4*)&KPs[4 * ty + i][kk];
            #pragma unroll
            for (int u = 0; u < 4; ++u) bv[u] = *(const float4*)&Vs[kk + u][4 * tx];
            #pragma unroll
            for (int i = 0; i < 4; ++i) {
                o[i][0] = fmaf(a[i].x, bv[0].x, o[i][0]);
                o[i][0] = fmaf(a[i].y, bv[1].x, o[i][0]);
                o[i][0] = fmaf(a[i].z, bv[2].x, o[i][0]);
                o[i][0] = fmaf(a[i].w, bv[3].x, o[i][0]);
                o[i][1] = fmaf(a[i].x, bv[0].y, o[i][1]);
                o[i][1] = fmaf(a[i].y, bv[1].y, o[i][1]);
                o[i][1] = fmaf(a[i].z, bv[2].y, o[i][1]);
                o[i][1] = fmaf(a[i].w, bv[3].y, o[i][1]);
                o[i][2] = fmaf(a[i].x, bv[0].z, o[i][2]);
                o[i][2] = fmaf(a[i].y, bv[1].z, o[i][2]);
                o[i][2] = fmaf(a[i].z, bv[2].z, o[i][2]);
                o[i][2] = fmaf(a[i].w, bv[3].z, o[i][2]);
                o[i][3] = fmaf(a[i].x, bv[0].w, o[i][3]);
                o[i][3] = fmaf(a[i].y, bv[1].w, o[i][3]);
                o[i][3] = fmaf(a[i].z, bv[2].w, o[i][3]);
                o[i][3] = fmaf(a[i].w, bv[3].w, o[i][3]);
            }
        }
    }

    // Epilogue: normalize and write ao[b][n][h*64 + d]
    float* aobase = ao + ((size_t)b * SEQ) * DIMC + h * 64 + 4 * tx;
    #pragma unroll
    for (int i = 0; i < 4; ++i) {
        const int n = q0 + 4 * ty + i;
        const float inv = 1.f / l_i[i];
        *(float4*)(aobase + (size_t)n * DIMC) =
            make_float4(o[i][0] * inv, o[i][1] * inv, o[i][2] * inv, o[i][3] * inv);
    }
}

// ---------------------------------------------------------------------------
// Kernel 3: output projection.  out[m,c] = sum_k ao[m,k]*w_proj[c,k] + b_proj[c]
// Same tiling as kernel 1.
// ---------------------------------------------------------------------------
__global__ __launch_bounds__(256) void proj_gemm_kernel(
    const float* __restrict__ ao, const float* __restrict__ wproj,
    const float* __restrict__ bproj, float* __restrict__ out)
{
    __shared__ float As[16][132];
    __shared__ float Bs[16][132];
    const int t  = threadIdx.x;
    const int tx = t & 15;
    const int ty = t >> 4;
    const int c0 = blockIdx.x * 128;
    const int m0 = blockIdx.y * 128;

    float acc[8][8];
    #pragma unroll
    for (int i = 0; i < 8; ++i)
        #pragma unroll
        for (int j = 0; j < 8; ++j) acc[i][j] = 0.f;

    for (int k0 = 0; k0 < DIMC; k0 += 16) {
        #pragma unroll
        for (int s = 0; s < 2; ++s) {
            const int f   = t + s * 256;
            const int row = f >> 2;
            const int col = (f & 3) << 2;
            float4 av = *(const float4*)(ao    + (size_t)(m0 + row) * DIMC + k0 + col);
            float4 bv = *(const float4*)(wproj + (size_t)(c0 + row) * DIMC + k0 + col);
            As[col + 0][row] = av.x; As[col + 1][row] = av.y;
            As[col + 2][row] = av.z; As[col + 3][row] = av.w;
            Bs[col + 0][row] = bv.x; Bs[col + 1][row] = bv.y;
            Bs[col + 2][row] = bv.z; Bs[col + 3][row] = bv.w;
        }
        __syncthreads();
        #pragma unroll
        for (int kk = 0; kk < 16; ++kk) {
            float4 a0 = *(const float4*)&As[kk][8 * ty];
            float4 a1 = *(const float4*)&As[kk][8 * ty + 4];
            float4 b0 = *(const float4*)&Bs[kk][8 * tx];
            float4 b1 = *(const float4*)&Bs[kk][8 * tx + 4];
            const float a[8]  = {a0.x, a0.y, a0.z, a0.w, a1.x, a1.y, a1.z, a1.w};
            const float bb[8] = {b0.x, b0.y, b0.z, b0.w, b1.x, b1.y, b1.z, b1.w};
            #pragma unroll
            for (int i = 0; i < 8; ++i)
                #pragma unroll
                for (int j = 0; j < 8; ++j)
                    acc[i][j] = fmaf(a[i], bb[j], acc[i][j]);
        }
        __syncthreads();
    }

    #pragma unroll
    for (int jj = 0; jj < 2; ++jj) {
        const int cg = c0 + 8 * tx + 4 * jj;
        float4 bias = *(const float4*)(bproj + cg);
        #pragma unroll
        for (int i = 0; i < 8; ++i) {
            const int m = m0 + 8 * ty + i;
            float4 v4 = make_float4(acc[i][4 * jj + 0] + bias.x,
                                    acc[i][4 * jj + 1] + bias.y,
                                    acc[i][4 * jj + 2] + bias.z,
                                    acc[i][4 * jj + 3] + bias.w);
            *(float4*)(out + (size_t)m * DIMC + cg) = v4;
        }
    }
}

// ---------------------------------------------------------------------------
extern "C" void kernel_launch(void* const* d_in, const int* in_sizes, int n_in,
                              void* d_out, int out_size, void* d_ws, size_t ws_size,
                              hipStream_t stream)
{
    const float* x     = (const float*)d_in[0];   // (8,1024,768)
    const float* wqkv  = (const float*)d_in[1];   // (2304,768)
    const float* wproj = (const float*)d_in[2];   // (768,768)
    const float* bproj = (const float*)d_in[3];   // (768,)
    const float* mask  = (const float*)d_in[4];   // (12,1024,1024)
    float* out = (float*)d_out;                   // (8,1024,768)

    float* ws = (float*)d_ws;
    float* qb = ws;                      // (B,H,N,HD)
    float* kb = qb + QKV_ELEMS;
    float* vb = kb + QKV_ELEMS;
    float* ao = vb + QKV_ELEMS;          // (B,N,DIMC)

    // QKV projection: M=8192, N=2304
    qkv_gemm_kernel<<<dim3(2304 / 128, 8192 / 128), 256, 0, stream>>>(
        x, wqkv, qb, kb, vb);

    // Attention: B*H*(N/64) blocks
    flash_attn_kernel<<<dim3(NBATCH * NHEAD * (SEQ / 64)), 256, 0, stream>>>(
        qb, kb, vb, mask, ao);

    // Output projection: M=8192, N=768
    proj_gemm_kernel<<<dim3(768 / 128, 8192 / 128), 256, 0, stream>>>(
        ao, wproj, bproj, out);
}

// Round 2
// 300.229 us; speedup vs baseline: 3.4608x; 3.4608x over previous
//
#include <hip/hip_runtime.h>
#include <math.h>
#include <stdint.h>

typedef unsigned short u16;
typedef __attribute__((ext_vector_type(8))) short short8;
typedef __attribute__((ext_vector_type(4))) float f32x4;

// fp32 -> bf16 round-to-nearest-even
__device__ __forceinline__ u16 f2b(float f) {
    union { float f; unsigned u; } v; v.f = f;
    unsigned r = v.u + 0x7fffu + ((v.u >> 16) & 1u);
    return (u16)(r >> 16);
}
__device__ __forceinline__ float b2f(u16 u) {
    union { float f; unsigned u; } v; v.u = ((unsigned)u) << 16; return v.f;
}

// async global->LDS, 16B per lane. lds base must be wave-uniform; HW adds lane*16.
#define GLL16(gsrc, ldsbase) __builtin_amdgcn_global_load_lds(                    \
    (__attribute__((address_space(1))) void*)(uintptr_t)(gsrc),                   \
    (__attribute__((address_space(3))) void*)(uint32_t)(uintptr_t)(ldsbase),      \
    16, 0, 0)

// ---------------------------------------------------------------------------
// K0: convert x/w_qkv/w_proj to bf16; gate = bf16(0.125*sigmoid(mask)).
// ---------------------------------------------------------------------------
#define NX4  1572864   // 6291456/4
#define NW14 442368
#define NW24 147456
#define NM4  3145728
#define NTOT4 (NX4 + NW14 + NW24 + NM4)   // 5308416

__global__ __launch_bounds__(256) void prep_kernel(
    const float4* __restrict__ x, const float4* __restrict__ wq,
    const float4* __restrict__ wp, const float4* __restrict__ mask,
    ushort4* __restrict__ xb, ushort4* __restrict__ wqb,
    ushort4* __restrict__ wpb, ushort4* __restrict__ gb)
{
    size_t i = (size_t)blockIdx.x * 256 + threadIdx.x;
    float4 v; ushort4* dst; size_t j;
    if (i < NX4)                       { j = i;                     v = x[j];    dst = xb;  }
    else if (i < NX4 + NW14)           { j = i - NX4;               v = wq[j];   dst = wqb; }
    else if (i < NX4 + NW14 + NW24)    { j = i - (NX4 + NW14);      v = wp[j];   dst = wpb; }
    else {
        j = i - (NX4 + NW14 + NW24);   v = mask[j];
        v.x = 0.125f / (1.f + __expf(-v.x));
        v.y = 0.125f / (1.f + __expf(-v.y));
        v.z = 0.125f / (1.f + __expf(-v.z));
        v.w = 0.125f / (1.f + __expf(-v.w));
        dst = gb;
    }
    ushort4 o; o.x = f2b(v.x); o.y = f2b(v.y); o.z = f2b(v.z); o.w = f2b(v.w);
    dst[j] = o;
}

// ---------------------------------------------------------------------------
// K1: QKV GEMM, bf16 MFMA 16x16x32. C[m,c] = sum_k xb[m,k]*wqkvb[c,k].
// 128x128 tile, BK=32, 4 waves each 64x64. LDS row-major [128][32] u16 with
// 16B-seg XOR swizzle (seg' = seg ^ (row&3)) to break bank conflicts.
// Scatters bf16 into q/k/v (B,H,N,64).
// ---------------------------------------------------------------------------
__global__ __launch_bounds__(256) void qkv_gemm(
    const u16* __restrict__ xb, const u16* __restrict__ wb,
    u16* __restrict__ qb, u16* __restrict__ kb, u16* __restrict__ vb)
{
    __shared__ u16 As[128 * 32];
    __shared__ u16 Bs[128 * 32];
    const int t = threadIdx.x, l = t & 63, w = t >> 6;
    const int wm = (w & 1) * 64, wn = (w >> 1) * 64;
    const int m0 = blockIdx.y * 128, c0 = blockIdx.x * 128;

    f32x4 acc[4][4];
    #pragma unroll
    for (int i = 0; i < 4; ++i)
        #pragma unroll
        for (int j = 0; j < 4; ++j) { f32x4 z = {0.f,0.f,0.f,0.f}; acc[i][j] = z; }

    // staging addressing: inst s covers rows s*64 + w*16 + (l>>2), seg (l&3)
    const int srow = l >> 2, sseg = l & 3;
    const int gcol = ((sseg ^ (srow & 3)) << 3);           // swizzled elem offset
    const u16* a0 = xb + (size_t)(m0 + w * 16 + srow) * 768 + gcol;
    const u16* a1 = a0 + (size_t)64 * 768;
    const u16* b0p = wb + (size_t)(c0 + w * 16 + srow) * 768 + gcol;
    const u16* b1p = b0p + (size_t)64 * 768;
    u16* ldsA0 = As + (w * 16) * 32;
    u16* ldsA1 = As + (64 + w * 16) * 32;
    u16* ldsB0 = Bs + (w * 16) * 32;
    u16* ldsB1 = Bs + (64 + w * 16) * 32;

    const int fr = l & 15, fq = l >> 4;
    const int fseg = (fq ^ (fr & 3)) << 3;                 // frag read swizzle

    for (int k0 = 0; k0 < 768; k0 += 32) {
        __syncthreads();
        GLL16(a0 + k0, ldsA0);
        GLL16(a1 + k0, ldsA1);
        GLL16(b0p + k0, ldsB0);
        GLL16(b1p + k0, ldsB1);
        __syncthreads();

        short8 af[4], bf[4];
        #pragma unroll
        for (int mt = 0; mt < 4; ++mt)
            af[mt] = *(const short8*)&As[(wm + mt * 16 + fr) * 32 + fseg];
        #pragma unroll
        for (int nt = 0; nt < 4; ++nt)
            bf[nt] = *(const short8*)&Bs[(wn + nt * 16 + fr) * 32 + fseg];
        #pragma unroll
        for (int mt = 0; mt < 4; ++mt)
            #pragma unroll
            for (int nt = 0; nt < 4; ++nt)
                acc[mt][nt] = __builtin_amdgcn_mfma_f32_16x16x32_bf16(
                    af[mt], bf[nt], acc[mt][nt], 0, 0, 0);
    }

    // epilogue: C row = m0+wm+mt*16+fq*4+r ; col = c0+wn+nt*16+fr
    const int b = m0 >> 10;
    #pragma unroll
    for (int nt = 0; nt < 4; ++nt) {
        const int c = c0 + wn + nt * 16 + fr;
        const int which = c / 768;
        const int rem = c - which * 768;
        const int h = rem >> 6, d = rem & 63;
        u16* dst = ((which == 0) ? qb : (which == 1) ? kb : vb)
                   + ((size_t)(b * 12 + h) * 1024) * 64 + d;
        #pragma unroll
        for (int mt = 0; mt < 4; ++mt)
            #pragma unroll
            for (int r = 0; r < 4; ++r) {
                const int m = m0 + wm + mt * 16 + fq * 4 + r;
                dst[(size_t)(m & 1023) * 64] = f2b(acc[mt][nt][r]);
            }
    }
}

// ---------------------------------------------------------------------------
// K2: transpose V (B,H,1024,64) -> Vt (B,H,64,1024), 64x64 tiles.
// ---------------------------------------------------------------------------
__global__ __launch_bounds__(256) void transpose_v(
    const u16* __restrict__ vb, u16* __restrict__ vt)
{
    __shared__ u16 L[64][72];
    const int t = threadIdx.x;
    const int bh = blockIdx.x >> 4, kt = blockIdx.x & 15;
    const u16* src = vb + ((size_t)bh * 1024 + kt * 64) * 64;
    {
        const int key = t >> 2, s = (t & 3) * 16;
        *(float4*)&L[key][s]     = *(const float4*)(src + (size_t)key * 64 + s);
        *(float4*)&L[key][s + 8] = *(const float4*)(src + (size_t)key * 64 + s + 8);
    }
    __syncthreads();
    {
        const int d = t >> 2, ks = (t & 3) * 16;
        union { u16 u[8]; float4 f; } p0, p1;
        #pragma unroll
        for (int j = 0; j < 8; ++j) p0.u[j] = L[ks + j][d];
        #pragma unroll
        for (int j = 0; j < 8; ++j) p1.u[j] = L[ks + 8 + j][d];
        u16* dst = vt + ((size_t)bh * 64 + d) * 1024 + kt * 64 + ks;
        *(float4*)dst = p0.f;
        *(float4*)(dst + 8) = p1.f;
    }
}

// ---------------------------------------------------------------------------
// K3: flash attention, bf16 MFMA. Block = (b,h,64-row q tile), 4 waves each
// owning 16 q rows. 16 key-chunks of 64. gate pre-multiplied w/ 0.125.
// LDS tiles [64][64] u16 row-major with 16B-seg XOR swizzle seg^(row&7).
// P round-trips through per-wave LDS (C-layout -> A-layout).
// ---------------------------------------------------------------------------
__global__ __launch_bounds__(256) void flash_attn(
    const u16* __restrict__ qb, const u16* __restrict__ kb,
    const u16* __restrict__ vt, const u16* __restrict__ gate,
    u16* __restrict__ aob)
{
    __shared__ u16 Qs[4096], Ks[4096], Vts[4096], Gs[4096], Ps[4096];
    const int t = threadIdx.x, l = t & 63, w = t >> 6;
    const int bid = blockIdx.x;
    const int h = bid >> 7, qt = (bid >> 3) & 15, b = bid & 7;
    const int q0 = qt * 64;
    const u16* hq = qb + (size_t)(b * 12 + h) * 1024 * 64;
    const u16* hk = kb + (size_t)(b * 12 + h) * 1024 * 64;
    const u16* hv = vt + (size_t)(b * 12 + h) * 64 * 1024;
    const u16* hg = gate + (size_t)h * 1024 * 1024;

    const int sr = l >> 3, ss = l & 7;
    const int sg = ((ss ^ (sr & 7)) << 3);        // swizzled global col (elems)
    const int j0 = w * 2, j1 = w * 2 + 1;

    // stage Q once (covered by first in-loop barrier's vmcnt drain)
    GLL16(hq + (size_t)(q0 + j0 * 8 + sr) * 64 + sg, Qs + j0 * 512);
    GLL16(hq + (size_t)(q0 + j1 * 8 + sr) * 64 + sg, Qs + j1 * 512);

    float m_i[4], l_i[4];
    f32x4 o[4];
    #pragma unroll
    for (int i = 0; i < 4; ++i) { m_i[i] = -1e30f; l_i[i] = 0.f; }
    #pragma unroll
    for (int nt = 0; nt < 4; ++nt) { f32x4 z = {0.f,0.f,0.f,0.f}; o[nt] = z; }

    const int fq = l >> 4, fr = l & 15;
    const int sega = ((fq ^ (fr & 7)) << 3);          // ka=0 frag seg offset
    const int segb = (((4 + fq) ^ (fr & 7)) << 3);    // ka=1

    for (int kt = 0; kt < 16; ++kt) {
        __syncthreads();
        GLL16(hk + (size_t)(kt * 64 + j0 * 8 + sr) * 64 + sg, Ks + j0 * 512);
        GLL16(hk + (size_t)(kt * 64 + j1 * 8 + sr) * 64 + sg, Ks + j1 * 512);
        GLL16(hv + (size_t)(j0 * 8 + sr) * 1024 + kt * 64 + sg, Vts + j0 * 512);
        GLL16(hv + (size_t)(j1 * 8 + sr) * 1024 + kt * 64 + sg, Vts + j1 * 512);
        GLL16(hg + (size_t)(q0 + j0 * 8 + sr) * 1024 + kt * 64 + sg, Gs + j0 * 512);
        GLL16(hg + (size_t)(q0 + j1 * 8 + sr) * 1024 + kt * 64 + sg, Gs + j1 * 512);
        __syncthreads();

        // S = Q . K^T  (scale folded into gate)
        short8 aq0 = *(const short8*)&Qs[(16 * w + fr) * 64 + sega];
        short8 aq1 = *(const short8*)&Qs[(16 * w + fr) * 64 + segb];
        f32x4 sv[4];
        #pragma unroll
        for (int nt = 0; nt < 4; ++nt) {
            short8 k0f = *(const short8*)&Ks[(nt * 16 + fr) * 64 + sega];
            short8 k1f = *(const short8*)&Ks[(nt * 16 + fr) * 64 + segb];
            f32x4 z = {0.f,0.f,0.f,0.f};
            z = __builtin_amdgcn_mfma_f32_16x16x32_bf16(aq0, k0f, z, 0, 0, 0);
            z = __builtin_amdgcn_mfma_f32_16x16x32_bf16(aq1, k1f, z, 0, 0, 0);
            sv[nt] = z;
        }

        // gate + online softmax (rows rloc = 16w + 4*fq + i, cols nt*16+fr)
        #pragma unroll
        for (int i = 0; i < 4; ++i) {
            const int rloc = 16 * w + 4 * fq + i;
            float sval[4];
            #pragma unroll
            for (int nt = 0; nt < 4; ++nt) {
                const int col = nt * 16 + fr;
                const float g = b2f(Gs[rloc * 64 + (((col >> 3) ^ (rloc & 7)) << 3) + (col & 7)]);
                sval[nt] = sv[nt][i] * g;
            }
            float mx = fmaxf(fmaxf(sval[0], sval[1]), fmaxf(sval[2], sval[3]));
            mx = fmaxf(mx, __shfl_xor(mx, 1, 16));
            mx = fmaxf(mx, __shfl_xor(mx, 2, 16));
            mx = fmaxf(mx, __shfl_xor(mx, 4, 16));
            mx = fmaxf(mx, __shfl_xor(mx, 8, 16));
            const float mnew = fmaxf(m_i[i], mx);
            const float alpha = __expf(m_i[i] - mnew);
            m_i[i] = mnew;
            float rs = 0.f;
            #pragma unroll
            for (int nt = 0; nt < 4; ++nt) {
                const float p = __expf(sval[nt] - mnew);
                rs += p;
                const int col = nt * 16 + fr, pr = 4 * fq + i;
                Ps[w * 1024 + pr * 64 + (((col >> 3) ^ (pr & 7)) << 3) + (col & 7)] = f2b(p);
            }
            rs += __shfl_xor(rs, 1, 16);
            rs += __shfl_xor(rs, 2, 16);
            rs += __shfl_xor(rs, 4, 16);
            rs += __shfl_xor(rs, 8, 16);
            l_i[i] = l_i[i] * alpha + rs;
            #pragma unroll
            for (int nt = 0; nt < 4; ++nt) o[nt][i] *= alpha;
        }

        // O += P . V  (per-wave Ps, no barrier needed)
        short8 ap0 = *(const short8*)&Ps[w * 1024 + fr * 64 + sega];
        short8 ap1 = *(const short8*)&Ps[w * 1024 + fr * 64 + segb];
        #pragma unroll
        for (int nt = 0; nt < 4; ++nt) {
            short8 v0 = *(const short8*)&Vts[(nt * 16 + fr) * 64 + sega];
            short8 v1 = *(const short8*)&Vts[(nt * 16 + fr) * 64 + segb];
            o[nt] = __builtin_amdgcn_mfma_f32_16x16x32_bf16(ap0, v0, o[nt], 0, 0, 0);
            o[nt] = __builtin_amdgcn_mfma_f32_16x16x32_bf16(ap1, v1, o[nt], 0, 0, 0);
        }
    }

    // epilogue -> aob (B,N,768) bf16
    #pragma unroll
    for (int i = 0; i < 4; ++i) {
        const float inv = 1.f / l_i[i];
        const int n = q0 + 16 * w + 4 * fq + i;
        const size_t rowoff = ((size_t)b * 1024 + n) * 768 + h * 64;
        #pragma unroll
        for (int nt = 0; nt < 4; ++nt)
            aob[rowoff + nt * 16 + fr] = f2b(o[nt][i] * inv);
    }
}

// ---------------------------------------------------------------------------
// K4: output projection, bf16 MFMA, fp32 out + bias.
// ---------------------------------------------------------------------------
__global__ __launch_bounds__(256) void proj_gemm(
    const u16* __restrict__ aob, const u16* __restrict__ wb,
    const float* __restrict__ bproj, float* __restrict__ out)
{
    __shared__ u16 As[128 * 32];
    __shared__ u16 Bs[128 * 32];
    const int t = threadIdx.x, l = t & 63, w = t >> 6;
    const int wm = (w & 1) * 64, wn = (w >> 1) * 64;
    const int m0 = blockIdx.y * 128, c0 = blockIdx.x * 128;

    f32x4 acc[4][4];
    #pragma unroll
    for (int i = 0; i < 4; ++i)
        #pragma unroll
        for (int j = 0; j < 4; ++j) { f32x4 z = {0.f,0.f,0.f,0.f}; acc[i][j] = z; }

    const int srow = l >> 2, sseg = l & 3;
    const int gcol = ((sseg ^ (srow & 3)) << 3);
    const u16* a0 = aob + (size_t)(m0 + w * 16 + srow) * 768 + gcol;
    const u16* a1 = a0 + (size_t)64 * 768;
    const u16* b0p = wb + (size_t)(c0 + w * 16 + srow) * 768 + gcol;
    const u16* b1p = b0p + (size_t)64 * 768;
    u16* ldsA0 = As + (w * 16) * 32;
    u16* ldsA1 = As + (64 + w * 16) * 32;
    u16* ldsB0 = Bs + (w * 16) * 32;
    u16* ldsB1 = Bs + (64 + w * 16) * 32;

    const int fr = l & 15, fq = l >> 4;
    const int fseg = (fq ^ (fr & 3)) << 3;

    for (int k0 = 0; k0 < 768; k0 += 32) {
        __syncthreads();
        GLL16(a0 + k0, ldsA0);
        GLL16(a1 + k0, ldsA1);
        GLL16(b0p + k0, ldsB0);
        GLL16(b1p + k0, ldsB1);
        __syncthreads();

        short8 af[4], bf[4];
        #pragma unroll
        for (int mt = 0; mt < 4; ++mt)
            af[mt] = *(const short8*)&As[(wm + mt * 16 + fr) * 32 + fseg];
        #pragma unroll
        for (int nt = 0; nt < 4; ++nt)
            bf[nt] = *(const short8*)&Bs[(wn + nt * 16 + fr) * 32 + fseg];
        #pragma unroll
        for (int mt = 0; mt < 4; ++mt)
            #pragma unroll
            for (int nt = 0; nt < 4; ++nt)
                acc[mt][nt] = __builtin_amdgcn_mfma_f32_16x16x32_bf16(
                    af[mt], bf[nt], acc[mt][nt], 0, 0, 0);
    }

    #pragma unroll
    for (int nt = 0; nt < 4; ++nt) {
        const int c = c0 + wn + nt * 16 + fr;
        const float bias = bproj[c];
        #pragma unroll
        for (int mt = 0; mt < 4; ++mt)
            #pragma unroll
            for (int r = 0; r < 4; ++r) {
                const int m = m0 + wm + mt * 16 + fq * 4 + r;
                out[(size_t)m * 768 + c] = acc[mt][nt][r] + bias;
            }
    }
}

// ---------------------------------------------------------------------------
extern "C" void kernel_launch(void* const* d_in, const int* in_sizes, int n_in,
                              void* d_out, int out_size, void* d_ws, size_t ws_size,
                              hipStream_t stream)
{
    const float* x     = (const float*)d_in[0];
    const float* wqkv  = (const float*)d_in[1];
    const float* wproj = (const float*)d_in[2];
    const float* bproj = (const float*)d_in[3];
    const float* mask  = (const float*)d_in[4];
    float* out = (float*)d_out;

    char* ws = (char*)d_ws;
    u16* gateb  = (u16*)(ws);               // 25,165,824 B
    u16* xb     = (u16*)(ws + 25165824);    // 12,582,912 B
    u16* vt     = xb;                       // aliases xb (xb dead after qkv_gemm)
    u16* wqkvb  = (u16*)(ws + 37748736);    //  3,538,944 B
    u16* wprojb = (u16*)(ws + 41287680);    //  1,179,648 B
    u16* qb     = (u16*)(ws + 42467328);    // 12,582,912 B
    u16* kb     = (u16*)(ws + 55050240);    // 12,582,912 B
    u16* vb     = (u16*)(ws + 67633152);    // 12,582,912 B
    u16* aob    = (u16*)(ws + 80216064);    // 12,582,912 B  (total 92.8 MB)

    prep_kernel<<<NTOT4 / 256, 256, 0, stream>>>(
        (const float4*)x, (const float4*)wqkv, (const float4*)wproj,
        (const float4*)mask,
        (ushort4*)xb, (ushort4*)wqkvb, (ushort4*)wprojb, (ushort4*)gateb);

    qkv_gemm<<<dim3(18, 64), 256, 0, stream>>>(xb, wqkvb, qb, kb, vb);

    transpose_v<<<1536, 256, 0, stream>>>(vb, vt);

    flash_attn<<<1536, 256, 0, stream>>>(qb, kb, vt, gateb, aob);

    proj_gemm<<<dim3(6, 64), 256, 0, stream>>>(aob, wprojb, bproj, out);
}

// Round 3
// 248.222 us; speedup vs baseline: 4.1859x; 1.2095x over previous
//
#include <hip/hip_runtime.h>
#include <math.h>
#include <stdint.h>

typedef unsigned short u16;
typedef __attribute__((ext_vector_type(8))) short short8;
typedef __attribute__((ext_vector_type(4))) float f32x4;

// gate scale: 0.125 (attn scale) * log2(e)  -> p = exp2(s * gate)
#define GATE_SCALE 0.18033688011112042f

#if __has_builtin(__builtin_amdgcn_exp2f)
#define FEXP2(x) __builtin_amdgcn_exp2f(x)
#else
#define FEXP2(x) exp2f(x)
#endif

// fp32 -> bf16 round-to-nearest-even
__device__ __forceinline__ u16 f2b(float f) {
    union { float f; unsigned u; } v; v.f = f;
    unsigned r = v.u + 0x7fffu + ((v.u >> 16) & 1u);
    return (u16)(r >> 16);
}
// fp32 -> bf16 round-half-up (2 ops; same 0.5-ulp bound, tiny bias)
__device__ __forceinline__ u16 f2b_hu(float f) {
    union { float f; unsigned u; } v; v.f = f;
    return (u16)((v.u + 0x8000u) >> 16);
}
__device__ __forceinline__ float b2f(u16 u) {
    union { float f; unsigned u; } v; v.u = ((unsigned)u) << 16; return v.f;
}

// async global->LDS, 16B per lane. lds base wave-uniform; HW adds lane*16.
#define GLL16(gsrc, ldsbase) __builtin_amdgcn_global_load_lds(                    \
    (__attribute__((address_space(1))) void*)(uintptr_t)(gsrc),                   \
    (__attribute__((address_space(3))) void*)(uint32_t)(uintptr_t)(ldsbase),      \
    16, 0, 0)

// ---------------------------------------------------------------------------
// K0a: convert x / w_qkv / w_proj to bf16.
// ---------------------------------------------------------------------------
#define NX4  1572864   // 6291456/4
#define NW14 442368
#define NW24 147456
#define NXW4 (NX4 + NW14 + NW24)   // 2162688

__global__ __launch_bounds__(256) void prep_xw(
    const float4* __restrict__ x, const float4* __restrict__ wq,
    const float4* __restrict__ wp,
    ushort4* __restrict__ xb, ushort4* __restrict__ wqb,
    ushort4* __restrict__ wpb)
{
    size_t i = (size_t)blockIdx.x * 256 + threadIdx.x;
    float4 v; ushort4* dst; size_t j;
    if (i < NX4)            { j = i;               v = x[j];  dst = xb;  }
    else if (i < NX4 + NW14){ j = i - NX4;         v = wq[j]; dst = wqb; }
    else                    { j = i - (NX4 + NW14);v = wp[j]; dst = wpb; }
    ushort4 o; o.x = f2b(v.x); o.y = f2b(v.y); o.z = f2b(v.z); o.w = f2b(v.w);
    dst[j] = o;
}

// ---------------------------------------------------------------------------
// K0b: gate = bf16(GATE_SCALE * sigmoid(mask)), permuted into MFMA C-fragment
// order. One block per (h, qt, kt) 64x64 tile; lane (w,l) owns the 16 S
// elements it will hold after QK^T: rows 16w+4fq+i, cols nt*16+fr, stored
// contiguously at tile*4096 + (w*64+l)*16, inner order idx = i*4+nt.
// ---------------------------------------------------------------------------
__global__ __launch_bounds__(256) void prep_gate(
    const float* __restrict__ mask, u16* __restrict__ gp)
{
    const int bid = blockIdx.x;                 // h*256 + qt*16 + kt
    const int h = bid >> 8, qt = (bid >> 4) & 15, kt = bid & 15;
    const int t = threadIdx.x, l = t & 63, w = t >> 6;
    const int fq = l >> 4, fr = l & 15;
    const float* mb = mask + ((size_t)h * 1024 + qt * 64 + 16 * w + 4 * fq) * 1024
                           + kt * 64 + fr;
    union { u16 u[16]; float4 f[2]; } vals;
    #pragma unroll
    for (int i = 0; i < 4; ++i)
        #pragma unroll
        for (int nt = 0; nt < 4; ++nt) {
            float m = mb[(size_t)i * 1024 + nt * 16];
            vals.u[i * 4 + nt] = f2b(GATE_SCALE / (1.f + __expf(-m)));
        }
    float4* dst = (float4*)(gp + (size_t)bid * 4096 + (w * 64 + l) * 16);
    dst[0] = vals.f[0];
    dst[1] = vals.f[1];
}

// ---------------------------------------------------------------------------
// K1: QKV GEMM, bf16 MFMA 16x16x32 (m97 structure, 128x128, BK=32).
// q/k written (B,H,N,64); V written TRANSPOSED (B,H,64,N) with packed
// ushort4 stores (n is the contiguous dim there).
// ---------------------------------------------------------------------------
__global__ __launch_bounds__(256) void qkv_gemm(
    const u16* __restrict__ xb, const u16* __restrict__ wb,
    u16* __restrict__ qb, u16* __restrict__ kb, u16* __restrict__ vb)
{
    __shared__ u16 As[128 * 32];
    __shared__ u16 Bs[128 * 32];
    const int t = threadIdx.x, l = t & 63, w = t >> 6;
    const int wm = (w & 1) * 64, wn = (w >> 1) * 64;
    const int m0 = blockIdx.y * 128, c0 = blockIdx.x * 128;

    f32x4 acc[4][4];
    #pragma unroll
    for (int i = 0; i < 4; ++i)
        #pragma unroll
        for (int j = 0; j < 4; ++j) { f32x4 z = {0.f,0.f,0.f,0.f}; acc[i][j] = z; }

    const int srow = l >> 2, sseg = l & 3;
    const int gcol = ((sseg ^ (srow & 3)) << 3);
    const u16* a0 = xb + (size_t)(m0 + w * 16 + srow) * 768 + gcol;
    const u16* a1 = a0 + (size_t)64 * 768;
    const u16* b0p = wb + (size_t)(c0 + w * 16 + srow) * 768 + gcol;
    const u16* b1p = b0p + (size_t)64 * 768;
    u16* ldsA0 = As + (w * 16) * 32;
    u16* ldsA1 = As + (64 + w * 16) * 32;
    u16* ldsB0 = Bs + (w * 16) * 32;
    u16* ldsB1 = Bs + (64 + w * 16) * 32;

    const int fr = l & 15, fq = l >> 4;
    const int fseg = (fq ^ (fr & 3)) << 3;

    for (int k0 = 0; k0 < 768; k0 += 32) {
        __syncthreads();
        GLL16(a0 + k0, ldsA0);
        GLL16(a1 + k0, ldsA1);
        GLL16(b0p + k0, ldsB0);
        GLL16(b1p + k0, ldsB1);
        __syncthreads();

        short8 af[4], bf[4];
        #pragma unroll
        for (int mt = 0; mt < 4; ++mt)
            af[mt] = *(const short8*)&As[(wm + mt * 16 + fr) * 32 + fseg];
        #pragma unroll
        for (int nt = 0; nt < 4; ++nt)
            bf[nt] = *(const short8*)&Bs[(wn + nt * 16 + fr) * 32 + fseg];
        #pragma unroll
        for (int mt = 0; mt < 4; ++mt)
            #pragma unroll
            for (int nt = 0; nt < 4; ++nt)
                acc[mt][nt] = __builtin_amdgcn_mfma_f32_16x16x32_bf16(
                    af[mt], bf[nt], acc[mt][nt], 0, 0, 0);
    }

    // epilogue: C row m = m0+wm+mt*16+fq*4+r ; col c = c0+wn+nt*16+fr
    const int b = m0 >> 10;
    const int n0 = m0 & 1023;
    #pragma unroll
    for (int nt = 0; nt < 4; ++nt) {
        const int c = c0 + wn + nt * 16 + fr;
        const int which = c / 768;                 // wave-uniform per nt
        const int rem = c - which * 768;
        const int h = rem >> 6, d = rem & 63;
        if (which < 2) {
            u16* dst = ((which == 0) ? qb : kb)
                       + ((size_t)(b * 12 + h) * 1024) * 64 + d;
            #pragma unroll
            for (int mt = 0; mt < 4; ++mt)
                #pragma unroll
                for (int r = 0; r < 4; ++r) {
                    const int n = n0 + wm + mt * 16 + fq * 4 + r;
                    dst[(size_t)n * 64] = f2b(acc[mt][nt][r]);
                }
        } else {
            // V transposed: vb[(b,h,d,n)], n contiguous -> pack 4 bf16
            u16* dst = vb + ((size_t)(b * 12 + h) * 64 + d) * 1024
                          + n0 + wm + fq * 4;
            #pragma unroll
            for (int mt = 0; mt < 4; ++mt) {
                ushort4 pk;
                pk.x = f2b(acc[mt][nt][0]); pk.y = f2b(acc[mt][nt][1]);
                pk.z = f2b(acc[mt][nt][2]); pk.w = f2b(acc[mt][nt][3]);
                *(ushort4*)(dst + mt * 16) = pk;
            }
        }
    }
}

// ---------------------------------------------------------------------------
// K2: flash attention, bf16 MFMA, no-max softmax (scores bounded: |S|<~7,
// exp2 never overflows fp32), deferred l-reduction, gate via permuted
// coalesced global loads. LDS 32KB: Qs/Ks/Vts + per-wave Ps.
// ---------------------------------------------------------------------------
__global__ __launch_bounds__(256) void flash_attn(
    const u16* __restrict__ qb, const u16* __restrict__ kb,
    const u16* __restrict__ vt, const u16* __restrict__ gperm,
    u16* __restrict__ aob)
{
    __shared__ u16 Qs[4096], Ks[4096], Vts[4096], Ps[4096];
    const int t = threadIdx.x, l = t & 63, w = t >> 6;
    const int bid = blockIdx.x;
    const int h = bid >> 7, qt = (bid >> 3) & 15, b = bid & 7;
    const int q0 = qt * 64;
    const u16* hq = qb + (size_t)(b * 12 + h) * 65536;
    const u16* hk = kb + (size_t)(b * 12 + h) * 65536;
    const u16* hv = vt + (size_t)(b * 12 + h) * 65536;
    const u16* hg = gperm + (size_t)(h * 256 + qt * 16) * 4096 + (w * 64 + l) * 16;

    const int sr = l >> 3, ss = l & 7;
    const int sg = ((ss ^ (sr & 7)) << 3);
    const int j0 = w * 2, j1 = w * 2 + 1;

    // stage Q once (first in-loop barrier drains vmcnt)
    GLL16(hq + (size_t)(q0 + j0 * 8 + sr) * 64 + sg, Qs + j0 * 512);
    GLL16(hq + (size_t)(q0 + j1 * 8 + sr) * 64 + sg, Qs + j1 * 512);

    float l_part[4] = {0.f, 0.f, 0.f, 0.f};
    f32x4 o[4];
    #pragma unroll
    for (int nt = 0; nt < 4; ++nt) { f32x4 z = {0.f,0.f,0.f,0.f}; o[nt] = z; }

    const int fq = l >> 4, fr = l & 15;
    const int sega = ((fq ^ (fr & 7)) << 3);
    const int segb = (((4 + fq) ^ (fr & 7)) << 3);

    for (int kt = 0; kt < 16; ++kt) {
        __syncthreads();
        GLL16(hk + (size_t)(kt * 64 + j0 * 8 + sr) * 64 + sg, Ks + j0 * 512);
        GLL16(hk + (size_t)(kt * 64 + j1 * 8 + sr) * 64 + sg, Ks + j1 * 512);
        GLL16(hv + (size_t)(j0 * 8 + sr) * 1024 + kt * 64 + sg, Vts + j0 * 512);
        GLL16(hv + (size_t)(j1 * 8 + sr) * 1024 + kt * 64 + sg, Vts + j1 * 512);
        const short8 g0 = *(const short8*)(hg + (size_t)kt * 4096);
        const short8 g1 = *(const short8*)(hg + (size_t)kt * 4096 + 8);
        __syncthreads();

        // S = Q . K^T
        short8 aq0 = *(const short8*)&Qs[(16 * w + fr) * 64 + sega];
        short8 aq1 = *(const short8*)&Qs[(16 * w + fr) * 64 + segb];
        f32x4 sv[4];
        #pragma unroll
        for (int nt = 0; nt < 4; ++nt) {
            short8 k0f = *(const short8*)&Ks[(nt * 16 + fr) * 64 + sega];
            short8 k1f = *(const short8*)&Ks[(nt * 16 + fr) * 64 + segb];
            f32x4 z = {0.f,0.f,0.f,0.f};
            z = __builtin_amdgcn_mfma_f32_16x16x32_bf16(aq0, k0f, z, 0, 0, 0);
            z = __builtin_amdgcn_mfma_f32_16x16x32_bf16(aq1, k1f, z, 0, 0, 0);
            sv[nt] = z;
        }

        // p = exp2(s * gate) ; accumulate per-lane row sums; write P to LDS
        #pragma unroll
        for (int i = 0; i < 4; ++i) {
            const int pr = 4 * fq + i;
            #pragma unroll
            for (int nt = 0; nt < 4; ++nt) {
                const int idx = i * 4 + nt;
                const float g = b2f((u16)(idx < 8 ? g0[idx] : g1[idx - 8]));
                const float p = FEXP2(sv[nt][i] * g);
                l_part[i] += p;
                const int col = nt * 16 + fr;
                Ps[w * 1024 + pr * 64 + (((col >> 3) ^ (pr & 7)) << 3) + (col & 7)]
                    = f2b_hu(p);
            }
        }

        // O += P . V  (per-wave Ps, no barrier)
        short8 ap0 = *(const short8*)&Ps[w * 1024 + fr * 64 + sega];
        short8 ap1 = *(const short8*)&Ps[w * 1024 + fr * 64 + segb];
        #pragma unroll
        for (int nt = 0; nt < 4; ++nt) {
            short8 v0 = *(const short8*)&Vts[(nt * 16 + fr) * 64 + sega];
            short8 v1 = *(const short8*)&Vts[(nt * 16 + fr) * 64 + segb];
            o[nt] = __builtin_amdgcn_mfma_f32_16x16x32_bf16(ap0, v0, o[nt], 0, 0, 0);
            o[nt] = __builtin_amdgcn_mfma_f32_16x16x32_bf16(ap1, v1, o[nt], 0, 0, 0);
        }
    }

    // one cross-lane l reduction per block (lanes sharing fq cover all 64 cols)
    float l_i[4];
    #pragma unroll
    for (int i = 0; i < 4; ++i) {
        float s = l_part[i];
        s += __shfl_xor(s, 1, 16);
        s += __shfl_xor(s, 2, 16);
        s += __shfl_xor(s, 4, 16);
        s += __shfl_xor(s, 8, 16);
        l_i[i] = s;
    }

    // epilogue -> aob (B,N,768) bf16
    #pragma unroll
    for (int i = 0; i < 4; ++i) {
        const float inv = 1.f / l_i[i];
        const int n = q0 + 16 * w + 4 * fq + i;
        const size_t rowoff = ((size_t)b * 1024 + n) * 768 + h * 64;
        #pragma unroll
        for (int nt = 0; nt < 4; ++nt)
            aob[rowoff + nt * 16 + fr] = f2b(o[nt][i] * inv);
    }
}

// ---------------------------------------------------------------------------
// K3: output projection, bf16 MFMA, fp32 out + bias.
// ---------------------------------------------------------------------------
__global__ __launch_bounds__(256) void proj_gemm(
    const u16* __restrict__ aob, const u16* __restrict__ wb,
    const float* __restrict__ bproj, float* __restrict__ out)
{
    __shared__ u16 As[128 * 32];
    __shared__ u16 Bs[128 * 32];
    const int t = threadIdx.x, l = t & 63, w = t >> 6;
    const int wm = (w & 1) * 64, wn = (w >> 1) * 64;
    const int m0 = blockIdx.y * 128, c0 = blockIdx.x * 128;

    f32x4 acc[4][4];
    #pragma unroll
    for (int i = 0; i < 4; ++i)
        #pragma unroll
        for (int j = 0; j < 4; ++j) { f32x4 z = {0.f,0.f,0.f,0.f}; acc[i][j] = z; }

    const int srow = l >> 2, sseg = l & 3;
    const int gcol = ((sseg ^ (srow & 3)) << 3);
    const u16* a0 = aob + (size_t)(m0 + w * 16 + srow) * 768 + gcol;
    const u16* a1 = a0 + (size_t)64 * 768;
    const u16* b0p = wb + (size_t)(c0 + w * 16 + srow) * 768 + gcol;
    const u16* b1p = b0p + (size_t)64 * 768;
    u16* ldsA0 = As + (w * 16) * 32;
    u16* ldsA1 = As + (64 + w * 16) * 32;
    u16* ldsB0 = Bs + (w * 16) * 32;
    u16* ldsB1 = Bs + (64 + w * 16) * 32;

    const int fr = l & 15, fq = l >> 4;
    const int fseg = (fq ^ (fr & 3)) << 3;

    for (int k0 = 0; k0 < 768; k0 += 32) {
        __syncthreads();
        GLL16(a0 + k0, ldsA0);
        GLL16(a1 + k0, ldsA1);
        GLL16(b0p + k0, ldsB0);
        GLL16(b1p + k0, ldsB1);
        __syncthreads();

        short8 af[4], bf[4];
        #pragma unroll
        for (int mt = 0; mt < 4; ++mt)
            af[mt] = *(const short8*)&As[(wm + mt * 16 + fr) * 32 + fseg];
        #pragma unroll
        for (int nt = 0; nt < 4; ++nt)
            bf[nt] = *(const short8*)&Bs[(wn + nt * 16 + fr) * 32 + fseg];
        #pragma unroll
        for (int mt = 0; mt < 4; ++mt)
            #pragma unroll
            for (int nt = 0; nt < 4; ++nt)
                acc[mt][nt] = __builtin_amdgcn_mfma_f32_16x16x32_bf16(
                    af[mt], bf[nt], acc[mt][nt], 0, 0, 0);
    }

    #pragma unroll
    for (int nt = 0; nt < 4; ++nt) {
        const int c = c0 + wn + nt * 16 + fr;
        const float bias = bproj[c];
        #pragma unroll
        for (int mt = 0; mt < 4; ++mt)
            #pragma unroll
            for (int r = 0; r < 4; ++r) {
                const int m = m0 + wm + mt * 16 + fq * 4 + r;
                out[(size_t)m * 768 + c] = acc[mt][nt][r] + bias;
            }
    }
}

// ---------------------------------------------------------------------------
extern "C" void kernel_launch(void* const* d_in, const int* in_sizes, int n_in,
                              void* d_out, int out_size, void* d_ws, size_t ws_size,
                              hipStream_t stream)
{
    const float* x     = (const float*)d_in[0];
    const float* wqkv  = (const float*)d_in[1];
    const float* wproj = (const float*)d_in[2];
    const float* bproj = (const float*)d_in[3];
    const float* mask  = (const float*)d_in[4];
    float* out = (float*)d_out;

    char* ws = (char*)d_ws;
    u16* gperm  = (u16*)(ws);               // 25,165,824 B
    u16* xb     = (u16*)(ws + 25165824);    // 12,582,912 B
    u16* wqkvb  = (u16*)(ws + 37748736);    //  3,538,944 B
    u16* wprojb = (u16*)(ws + 41287680);    //  1,179,648 B
    u16* qb     = (u16*)(ws + 42467328);    // 12,582,912 B
    u16* kb     = (u16*)(ws + 55050240);    // 12,582,912 B
    u16* vb     = (u16*)(ws + 67633152);    // 12,582,912 B (transposed: B,H,64,N)
    u16* aob    = (u16*)(ws + 80216064);    // 12,582,912 B  (total 92.8 MB)

    prep_xw<<<NXW4 / 256, 256, 0, stream>>>(
        (const float4*)x, (const float4*)wqkv, (const float4*)wproj,
        (ushort4*)xb, (ushort4*)wqkvb, (ushort4*)wprojb);

    prep_gate<<<3072, 256, 0, stream>>>(mask, gperm);

    qkv_gemm<<<dim3(18, 64), 256, 0, stream>>>(xb, wqkvb, qb, kb, vb);

    flash_attn<<<1536, 256, 0, stream>>>(qb, kb, vb, gperm, aob);

    proj_gemm<<<dim3(6, 64), 256, 0, stream>>>(aob, wprojb, bproj, out);
}